// Round 10
// baseline (20645.859 us; speedup 1.0000x reference)
//
#include <hip/hip_runtime.h>
#include <math.h>

#define T_STEPS 8192
#define I_DIM   64
#define H_DIM   2048
#define O_DIM   128
#define NBLK    256     // one block per CU; each owns 8 h-indices (32 gate rows)
#define NTHR    512     // 8 waves
#define NSLOT   4       // h slot ring depth
#define NAN_BITS 0x7FC00000u

typedef float        v4f __attribute__((ext_vector_type(4)));
typedef unsigned int v4u __attribute__((ext_vector_type(4)));

__device__ __forceinline__ float sigmoid_f(float x) {
    return 1.0f / (1.0f + __expf(-x));
}
__device__ __forceinline__ float tanh_fast(float x) {
    // 2*sigmoid(2x)-1; saturates correctly for |x| large
    return 2.0f / (1.0f + __expf(-2.0f * x)) - 1.0f;
}

// DPP wave64 sum (VALU pipe, not LDS pipe). Lane 63 ends with the full sum.
template <int CTRL>
__device__ __forceinline__ float dpp_add(float v) {
    int s = __builtin_amdgcn_update_dpp(0, __builtin_bit_cast(int, v),
                                        CTRL, 0xF, 0xF, true);
    return v + __builtin_bit_cast(float, s);
}
__device__ __forceinline__ float wave_sum64_lane63(float v) {
    v = dpp_add<0x111>(v);  // row_shr:1
    v = dpp_add<0x112>(v);  // row_shr:2
    v = dpp_add<0x114>(v);  // row_shr:4
    v = dpp_add<0x118>(v);  // row_shr:8
    v = dpp_add<0x142>(v);  // row_bcast:15
    v = dpp_add<0x143>(v);  // row_bcast:31 -> lane63 = sum(0..63)
    return v;
}

__global__ void init_ws_kernel(unsigned int* Hbits) {
    int tid = blockIdx.x * blockDim.x + threadIdx.x;
    if (tid < NSLOT * H_DIM) {
        // slot 0 = h_0 = 0.0f; slots 1..3 = NaN sentinel ("not ready")
        Hbits[tid] = (tid < H_DIM) ? 0u : NAN_BITS;
    }
}

// Persistent LSTM recurrence. Proven LLC fabric (agent-scope data-as-flag ring,
// coalesced 32B publish/reset from wave0 lanes<8 — WRITE signature 131 MB).
// Round-10 changes: (1) poll = ONE global_load_dwordx4 sc1 (agent, NOT sc0+sc1
// system — round-4 bug) per thread on contiguous 16B; (2) s_sleep(1);
// (3) barrier 2 removed: lane63s post gates to gbuf (NaN sentinel), wave 0
// spins on LDS, computes elementwise alone, publishes. hbuf single-buffer is
// safe without barrier 2: staging h(t+1) requires remote publish(t+1) which
// transitively requires this CU's publish(t) which requires all local dots(t).
__global__ __launch_bounds__(NTHR, 2) void lstm_persistent(
    const float* __restrict__ x,     // [T, 64]
    const float* __restrict__ Wih,   // [8192, 64]
    const float* __restrict__ Whh,   // [8192, 2048]
    const float* __restrict__ bih,   // [8192]
    const float* __restrict__ bhh,   // [8192]
    unsigned int* __restrict__ Hbits)// [NSLOT][2048] in ws (float bits)
{
    const int cu   = blockIdx.x;
    const int tid  = threadIdx.x;
    const int w    = tid >> 6;
    const int lane = tid & 63;

    __shared__ float hbuf[H_DIM];        // 8 KB, hbuf[k] = h[k]
    __shared__ float xbuf[I_DIM];
    __shared__ unsigned int gbits[32];   // gbits[g*8+j] = gate-g preact of h-sub j (NaN = pending)

    const int q    = w >> 1;
    const int joff = (w & 1) * 4;
    const int row0 = q * H_DIM + cu * 8 + joff;

    // ---- one-time: W_hh fragment into registers ----
    // wreg[i][m] = W[row0+i][m*256 + lane*4 .. +3]   (coalesced 16B loads)
    v4f wreg[4][8];
#pragma unroll
    for (int i = 0; i < 4; i++) {
        const float* p = Whh + (size_t)(row0 + i) * H_DIM + lane * 4;
#pragma unroll
        for (int m = 0; m < 8; m++)
            wreg[i][m] = *(const v4f*)(p + m * 256);
    }
    // x-part: lane handles row (row0 + (lane>>4)), k-range (lane&15)*4 .. +4
    float xw[4];
    {
        const int xr = row0 + (lane >> 4);
        const float* p = Wih + (size_t)xr * I_DIM + (lane & 15) * 4;
#pragma unroll
        for (int m = 0; m < 4; m++) xw[m] = p[m];
    }
    // biases + cell state: wave 0 lanes 0..7 only (sole elementwise owner)
    float bias[4] = {0.f, 0.f, 0.f, 0.f};
    if (w == 0 && lane < 8) {
#pragma unroll
        for (int g = 0; g < 4; g++) {
            int r = g * H_DIM + cu * 8 + lane;
            bias[g] = bih[r] + bhh[r];
        }
    }
    float cstate = 0.0f;

    // init gbuf sentinels
    if (tid < 32) gbits[tid] = NAN_BITS;
    __syncthreads();

    volatile unsigned int* vg = gbits;

    for (int t = 0; t < T_STEPS; t++) {
        const int slot_r = t & (NSLOT - 1);
        const int slot_w = (t + 1) & (NSLOT - 1);
        const int slot_z = (t + 2) & (NSLOT - 1);

        // hoist the independent x load above the spin
        float xv_own = (tid < I_DIM) ? x[(size_t)t * I_DIM + tid] : 0.0f;

        // ---- 1. poll own contiguous 16B of h_t (data-as-flag), stage to LDS ----
        {
            const unsigned int* Hr = Hbits + slot_r * H_DIM + tid * 4;
            v4u u;
            for (;;) {
                asm volatile(
                    "global_load_dwordx4 %0, %1, off sc1\n\t"
                    "s_waitcnt vmcnt(0)"
                    : "=v"(u) : "v"(Hr) : "memory");
                bool miss = (u[0] == NAN_BITS) | (u[1] == NAN_BITS) |
                            (u[2] == NAN_BITS) | (u[3] == NAN_BITS);
                if (!miss) break;
                __builtin_amdgcn_s_sleep(1);
            }
            *(v4u*)&hbuf[tid * 4] = u;   // ds_write_b128, contiguous
            if (tid < I_DIM) xbuf[tid] = xv_own;
        }
        // reset own chunk 2 slots ahead (holds h_{t-2}, fully consumed, skew<=1).
        // Coalesced: 8 lanes of wave 0, one 32B transaction. DO NOT scatter.
        if (w == 0 && lane < 8) {
            __hip_atomic_store(Hbits + slot_z * H_DIM + cu * 8 + lane, NAN_BITS,
                               __ATOMIC_RELAXED, __HIP_MEMORY_SCOPE_AGENT);
        }
        __syncthreads();   // the ONLY barrier per step

        // ---- 2. dot products: 4 rows per wave, 8 x (ds_read_b128 + packed FMA) ----
        v4f av0 = {0.f,0.f,0.f,0.f}, av1 = {0.f,0.f,0.f,0.f};
        v4f av2 = {0.f,0.f,0.f,0.f}, av3 = {0.f,0.f,0.f,0.f};
#pragma unroll
        for (int m = 0; m < 8; m++) {
            v4f hv = *(const v4f*)&hbuf[m * 256 + lane * 4];
            av0 += wreg[0][m] * hv;
            av1 += wreg[1][m] * hv;
            av2 += wreg[2][m] * hv;
            av3 += wreg[3][m] * hv;
        }
        float acc0 = (av0[0] + av0[1]) + (av0[2] + av0[3]);
        float acc1 = (av1[0] + av1[1]) + (av1[2] + av1[3]);
        float acc2 = (av2[0] + av2[1]) + (av2[2] + av2[3]);
        float acc3 = (av3[0] + av3[1]) + (av3[2] + av3[3]);
        {   // fold in W_ih * x_t
            float xp = 0.f;
            const int b = (lane & 15) * 4;
#pragma unroll
            for (int m = 0; m < 4; m++) xp += xw[m] * xbuf[b + m];
            const int sel = lane >> 4;
            acc0 += (sel == 0) ? xp : 0.0f;
            acc1 += (sel == 1) ? xp : 0.0f;
            acc2 += (sel == 2) ? xp : 0.0f;
            acc3 += (sel == 3) ? xp : 0.0f;
        }
        // ---- 3. DPP reduce (VALU pipe); lane 63 posts to gbuf (LDS) ----
        acc0 = wave_sum64_lane63(acc0);
        acc1 = wave_sum64_lane63(acc1);
        acc2 = wave_sum64_lane63(acc2);
        acc3 = wave_sum64_lane63(acc3);
        if (lane == 63) {
            vg[q * 8 + joff + 0] = __float_as_uint(acc0);
            vg[q * 8 + joff + 1] = __float_as_uint(acc1);
            vg[q * 8 + joff + 2] = __float_as_uint(acc2);
            vg[q * 8 + joff + 3] = __float_as_uint(acc3);
        }

        // ---- 4. wave 0 alone: spin on gbuf sentinels, elementwise, publish ----
        // Finite dot products can never equal the NaN bit pattern.
        if (w == 0 && lane < 8) {
            unsigned int g0, g1, g2, g3;
            do {
                g0 = vg[0 * 8 + lane];
                g1 = vg[1 * 8 + lane];
                g2 = vg[2 * 8 + lane];
                g3 = vg[3 * 8 + lane];
            } while (__any((g0 == NAN_BITS) | (g1 == NAN_BITS) |
                           (g2 == NAN_BITS) | (g3 == NAN_BITS)));
            float iv = sigmoid_f(__uint_as_float(g0) + bias[0]);
            float fv = sigmoid_f(__uint_as_float(g1) + bias[1]);
            float gv = tanh_fast(__uint_as_float(g2) + bias[2]);
            float ov = sigmoid_f(__uint_as_float(g3) + bias[3]);
            cstate = fv * cstate + iv * gv;
            float hval = ov * tanh_fast(cstate);
            // publish first (latency-critical), then re-arm sentinels.
            // Re-arm precedes barrier 1 of t+1, which precedes all t+1 posts.
            __hip_atomic_store(Hbits + slot_w * H_DIM + cu * 8 + lane,
                               __float_as_uint(hval),
                               __ATOMIC_RELAXED, __HIP_MEMORY_SCOPE_AGENT);
            vg[0 * 8 + lane] = NAN_BITS;
            vg[1 * 8 + lane] = NAN_BITS;
            vg[2 * 8 + lane] = NAN_BITS;
            vg[3 * 8 + lane] = NAN_BITS;
        }
        // waves 1..7 fall through to the next poll; they cannot touch hbuf
        // until slot t+1 is ready, which transitively requires all local dots.
    }
}

// Final linear: out[o] = h_T . W_lin[o,:] + b_lin[o].  One wave per output.
// h_T lives in slot (T & 3) == 0.
__global__ void final_linear(const float* __restrict__ hT,
                             const float* __restrict__ Wlin,
                             const float* __restrict__ blin,
                             float* __restrict__ out)
{
    int gw   = (blockIdx.x * blockDim.x + threadIdx.x) >> 6;
    int lane = threadIdx.x & 63;
    if (gw < O_DIM) {
        const float* wp = Wlin + (size_t)gw * H_DIM;
        float s = 0.f;
        for (int k = lane; k < H_DIM; k += 64)
            s += wp[k] * hT[k];
#pragma unroll
        for (int off = 32; off; off >>= 1) s += __shfl_xor(s, off, 64);
        if (lane == 0) out[gw] = s + blin[gw];
    }
}

extern "C" void kernel_launch(void* const* d_in, const int* in_sizes, int n_in,
                              void* d_out, int out_size, void* d_ws, size_t ws_size,
                              hipStream_t stream)
{
    const float* x    = (const float*)d_in[0];
    const float* Wih  = (const float*)d_in[1];
    const float* Whh  = (const float*)d_in[2];
    const float* bih  = (const float*)d_in[3];
    const float* bhh  = (const float*)d_in[4];
    const float* Wlin = (const float*)d_in[5];
    const float* blin = (const float*)d_in[6];
    float* out = (float*)d_out;

    unsigned int* Hbits = (unsigned int*)d_ws;

    hipLaunchKernelGGL(init_ws_kernel, dim3((NSLOT * H_DIM + 255) / 256), dim3(256),
                       0, stream, Hbits);

    void* args[] = { (void*)&x, (void*)&Wih, (void*)&Whh, (void*)&bih, (void*)&bhh,
                     (void*)&Hbits };
    (void)hipLaunchCooperativeKernel(reinterpret_cast<void*>(lstm_persistent),
                                     dim3(NBLK), dim3(NTHR), args, 0, stream);

    // h_T is in slot (T_STEPS & 3) == 0
    hipLaunchKernelGGL(final_linear, dim3(32), dim3(256), 0, stream,
                       (const float*)Hbits, Wlin, blin, out);
}